// Round 3
// 501.733 us; speedup vs baseline: 1.0188x; 1.0188x over previous
//
#include <hip/hip_runtime.h>
#include <math.h>

// Problem constants (from reference): x [B=16, nH=16, hd=64, H=64, W=64] fp32
#define BB   16
#define NH   16
#define HD   64
#define HW   4096        // H*W = 64*64, contiguous per (b,nh,hd) slice
#define BN   4           // bottleneck dim
#define SEQ  16          // L = nH tokens
#define NSLICE (BB*NH*HD)   // 16384 slices of 4096 floats each
#define LN_EPS 1e-5f

// native clang vector type: __builtin_nontemporal_store requires this
// (HIP's float4 is a HIP_vector_type class and is rejected by the builtin)
typedef float vfloat4 __attribute__((ext_vector_type(4)));

// ---------------------------------------------------------------------------
// Kernel 1: mean-pool each contiguous 4096-float slice -> pooled[16384]
// Plain (allocating) loads on purpose: this pass populates the 256 MiB
// Infinity Cache with x, which add_kernel re-reads ~40 us later.
// ---------------------------------------------------------------------------
__global__ __launch_bounds__(256) void pool_kernel(const float* __restrict__ x,
                                                   float* __restrict__ pooled) {
    const int slice = blockIdx.x;                    // b*NH*HD + nh*HD + hd
    const float4* xp = (const float4*)(x + (size_t)slice * HW);
    const int t = threadIdx.x;

    float s = 0.f;
#pragma unroll
    for (int k = 0; k < 4; ++k) {                    // 4 float4 per thread
        float4 v = xp[t + k * 256];
        s += v.x + v.y + v.z + v.w;
    }
    // wave-64 reduce
#pragma unroll
    for (int off = 32; off > 0; off >>= 1) s += __shfl_down(s, off);

    __shared__ float red[4];
    if ((t & 63) == 0) red[t >> 6] = s;
    __syncthreads();
    if (t == 0) pooled[slice] = (red[0] + red[1] + red[2] + red[3]) * (1.0f / HW);
}

// ---------------------------------------------------------------------------
// Kernel 2: the whole bottleneck (compress -> MHA -> out_proj -> expand -> LN)
// One block, 256 threads; thread t handles token (b = t>>4, l = t&15).
// Writes delta[b,l,d] = LN(residual + gate*expanded)[d] - residual[d].
// ---------------------------------------------------------------------------
__global__ __launch_bounds__(256) void tiny_kernel(
    const float* __restrict__ pooled,
    const float* __restrict__ cw,  const float* __restrict__ cb,
    const float* __restrict__ ipw, const float* __restrict__ ipb,
    const float* __restrict__ opw, const float* __restrict__ opb,
    const float* __restrict__ ew,  const float* __restrict__ eb,
    const float* __restrict__ lw,  const float* __restrict__ lb,
    const float* __restrict__ gate,
    float* __restrict__ delta)
{
    const int t = threadIdx.x;            // t = b*16 + l
    const float* row = pooled + t * HD;   // residual for this token, 64 floats

    // compress: xc[e] = row . cw[e,:] + cb[e]
    float xc[BN];
#pragma unroll
    for (int e = 0; e < BN; ++e) {
        float acc = cb[e];
#pragma unroll
        for (int d = 0; d < HD; ++d) acc += row[d] * cw[e * HD + d];
        xc[e] = acc;
    }

    // qkv: in_proj_w is [12,4] row-major; q=rows 0..3, k=4..7, v=8..11
    float q[BN], k[BN], v[BN];
#pragma unroll
    for (int j = 0; j < BN; ++j) {
        float a0 = ipb[j], a1 = ipb[j + 4], a2 = ipb[j + 8];
#pragma unroll
        for (int e = 0; e < BN; ++e) {
            a0 += xc[e] * ipw[j * BN + e];
            a1 += xc[e] * ipw[(j + 4) * BN + e];
            a2 += xc[e] * ipw[(j + 8) * BN + e];
        }
        q[j] = a0; k[j] = a1; v[j] = a2;
    }

    // share k, v across the 16 tokens of each batch via LDS
    __shared__ float sk[256][BN];
    __shared__ float sv[256][BN];
#pragma unroll
    for (int e = 0; e < BN; ++e) { sk[t][e] = k[e]; sv[t][e] = v[e]; }
    __syncthreads();

    // 2 heads, dh=2: head h uses components {2h, 2h+1}
    const int base = t & ~15;                       // first token of this batch
    const float inv_sqrt_dh = 0.7071067811865476f;  // 1/sqrt(2)
    float o[BN];
#pragma unroll
    for (int h = 0; h < 2; ++h) {
        float sc[SEQ];
        float mx = -1e30f;
#pragma unroll
        for (int j = 0; j < SEQ; ++j) {
            float s = (q[2*h]   * sk[base + j][2*h] +
                       q[2*h+1] * sk[base + j][2*h+1]) * inv_sqrt_dh;
            sc[j] = s;
            mx = fmaxf(mx, s);
        }
        float sum = 0.f;
#pragma unroll
        for (int j = 0; j < SEQ; ++j) { sc[j] = expf(sc[j] - mx); sum += sc[j]; }
        const float inv = 1.0f / sum;
        float o0 = 0.f, o1 = 0.f;
#pragma unroll
        for (int j = 0; j < SEQ; ++j) {
            float p = sc[j] * inv;
            o0 += p * sv[base + j][2*h];
            o1 += p * sv[base + j][2*h+1];
        }
        o[2*h] = o0; o[2*h+1] = o1;
    }

    // out_proj: xa[e] = o . opw[e,:] + opb[e]
    float xa[BN];
#pragma unroll
    for (int e = 0; e < BN; ++e) {
        float a = opb[e];
#pragma unroll
        for (int e2 = 0; e2 < BN; ++e2) a += o[e2] * opw[e * BN + e2];
        xa[e] = a;
    }

    const float g = gate[0];

    // expand + residual + LayerNorm over hd=64
    float y[HD];
    float mu = 0.f;
#pragma unroll
    for (int d = 0; d < HD; ++d) {
        float a = eb[d];
#pragma unroll
        for (int e = 0; e < BN; ++e) a += xa[e] * ew[d * BN + e];
        float yy = row[d] + g * a;
        y[d] = yy;
        mu += yy;
    }
    mu *= (1.0f / HD);
    float var = 0.f;
#pragma unroll
    for (int d = 0; d < HD; ++d) { float z = y[d] - mu; var += z * z; }
    var *= (1.0f / HD);
    const float rs = rsqrtf(var + LN_EPS);

#pragma unroll
    for (int d = 0; d < HD; ++d) {
        float outp = (y[d] - mu) * rs * lw[d] + lb[d];
        delta[t * HD + d] = outp - row[d];
    }
}

// ---------------------------------------------------------------------------
// Kernel 3: out = x + delta[slice], broadcast over the 4096 floats of a slice
// NONTEMPORAL stores for out: the Infinity Cache is memory-side (writes
// allocate), so out's 256 MiB of stores would otherwise evict the L3-resident
// copy of x that pool_kernel just established. With nt stores, x stays
// resident and this kernel's x-read is served from L3, not HBM.
// ---------------------------------------------------------------------------
__global__ __launch_bounds__(256) void add_kernel(const float* __restrict__ x,
                                                  const float* __restrict__ delta,
                                                  float* __restrict__ out) {
    const int slice = blockIdx.x;
    const float dv = delta[slice];          // block-uniform scalar
    const size_t off = (size_t)slice * HW;
    const vfloat4* xp = (const vfloat4*)(x + off);
    vfloat4* op = (vfloat4*)(out + off);
    const int t = threadIdx.x;
#pragma unroll
    for (int kk = 0; kk < 4; ++kk) {
        vfloat4 vv = xp[t + kk * 256];
        vv += dv;                           // native vector: element-wise add
        __builtin_nontemporal_store(vv, op + t + kk * 256);
    }
}

// ---------------------------------------------------------------------------
extern "C" void kernel_launch(void* const* d_in, const int* in_sizes, int n_in,
                              void* d_out, int out_size, void* d_ws, size_t ws_size,
                              hipStream_t stream) {
    const float* x   = (const float*)d_in[0];
    const float* cw  = (const float*)d_in[1];
    const float* cb  = (const float*)d_in[2];
    const float* ipw = (const float*)d_in[3];
    const float* ipb = (const float*)d_in[4];
    const float* opw = (const float*)d_in[5];
    const float* opb = (const float*)d_in[6];
    const float* ew  = (const float*)d_in[7];
    const float* eb  = (const float*)d_in[8];
    const float* lw  = (const float*)d_in[9];
    const float* lb  = (const float*)d_in[10];
    const float* gate = (const float*)d_in[11];
    float* out = (float*)d_out;

    float* pooled = (float*)d_ws;           // 16384 floats
    float* delta  = pooled + NSLICE;        // 16384 floats

    pool_kernel<<<NSLICE, 256, 0, stream>>>(x, pooled);
    tiny_kernel<<<1, 256, 0, stream>>>(pooled, cw, cb, ipw, ipb, opw, opb,
                                       ew, eb, lw, lb, gate, delta);
    add_kernel<<<NSLICE, 256, 0, stream>>>(x, delta, out);
}

// Round 5
// 500.270 us; speedup vs baseline: 1.0218x; 1.0029x over previous
//
#include <hip/hip_runtime.h>
#include <math.h>

// Problem constants (from reference): x [B=16, nH=16, hd=64, H=64, W=64] fp32
#define BB   16
#define NH   16
#define HD   64
#define HW   4096        // H*W = 64*64, contiguous per (b,nh,hd) slice
#define BN   4           // bottleneck dim
#define SEQ  16          // L = nH tokens
#define NSLICE (BB*NH*HD)   // 16384 slices of 4096 floats each
#define LN_EPS 1e-5f

// native clang vector type: __builtin_nontemporal_store requires this
// (HIP's float4 is a HIP_vector_type class and is rejected by the builtin)
typedef float vfloat4 __attribute__((ext_vector_type(4)));

// ---------------------------------------------------------------------------
// Kernel 1: mean-pool each contiguous 4096-float slice -> pooled[16384]
// Plain (allocating) loads on purpose: this pass populates the 256 MiB
// Infinity Cache with x, which add_kernel re-reads ~40 us later.
// Traverses slices FORWARD (0 -> 16383).
// ---------------------------------------------------------------------------
__global__ __launch_bounds__(256) void pool_kernel(const float* __restrict__ x,
                                                   float* __restrict__ pooled) {
    const int slice = blockIdx.x;                    // b*NH*HD + nh*HD + hd
    const float4* xp = (const float4*)(x + (size_t)slice * HW);
    const int t = threadIdx.x;

    float s = 0.f;
#pragma unroll
    for (int k = 0; k < 4; ++k) {                    // 4 float4 per thread
        float4 v = xp[t + k * 256];
        s += v.x + v.y + v.z + v.w;
    }
    // wave-64 reduce
#pragma unroll
    for (int off = 32; off > 0; off >>= 1) s += __shfl_down(s, off);

    __shared__ float red[4];
    if ((t & 63) == 0) red[t >> 6] = s;
    __syncthreads();
    if (t == 0) pooled[slice] = (red[0] + red[1] + red[2] + red[3]) * (1.0f / HW);
}

// ---------------------------------------------------------------------------
// Kernel 2: the whole bottleneck (compress -> MHA -> out_proj -> expand -> LN)
// One block, 256 threads; thread t handles token (b = t>>4, l = t&15).
// Writes delta[b,l,d] = LN(residual + gate*expanded)[d] - residual[d].
// ---------------------------------------------------------------------------
__global__ __launch_bounds__(256) void tiny_kernel(
    const float* __restrict__ pooled,
    const float* __restrict__ cw,  const float* __restrict__ cb,
    const float* __restrict__ ipw, const float* __restrict__ ipb,
    const float* __restrict__ opw, const float* __restrict__ opb,
    const float* __restrict__ ew,  const float* __restrict__ eb,
    const float* __restrict__ lw,  const float* __restrict__ lb,
    const float* __restrict__ gate,
    float* __restrict__ delta)
{
    const int t = threadIdx.x;            // t = b*16 + l
    const float* row = pooled + t * HD;   // residual for this token, 64 floats

    // compress: xc[e] = row . cw[e,:] + cb[e]
    float xc[BN];
#pragma unroll
    for (int e = 0; e < BN; ++e) {
        float acc = cb[e];
#pragma unroll
        for (int d = 0; d < HD; ++d) acc += row[d] * cw[e * HD + d];
        xc[e] = acc;
    }

    // qkv: in_proj_w is [12,4] row-major; q=rows 0..3, k=4..7, v=8..11
    float q[BN], k[BN], v[BN];
#pragma unroll
    for (int j = 0; j < BN; ++j) {
        float a0 = ipb[j], a1 = ipb[j + 4], a2 = ipb[j + 8];
#pragma unroll
        for (int e = 0; e < BN; ++e) {
            a0 += xc[e] * ipw[j * BN + e];
            a1 += xc[e] * ipw[(j + 4) * BN + e];
            a2 += xc[e] * ipw[(j + 8) * BN + e];
        }
        q[j] = a0; k[j] = a1; v[j] = a2;
    }

    // share k, v across the 16 tokens of each batch via LDS
    __shared__ float sk[256][BN];
    __shared__ float sv[256][BN];
#pragma unroll
    for (int e = 0; e < BN; ++e) { sk[t][e] = k[e]; sv[t][e] = v[e]; }
    __syncthreads();

    // 2 heads, dh=2: head h uses components {2h, 2h+1}
    const int base = t & ~15;                       // first token of this batch
    const float inv_sqrt_dh = 0.7071067811865476f;  // 1/sqrt(2)
    float o[BN];
#pragma unroll
    for (int h = 0; h < 2; ++h) {
        float sc[SEQ];
        float mx = -1e30f;
#pragma unroll
        for (int j = 0; j < SEQ; ++j) {
            float s = (q[2*h]   * sk[base + j][2*h] +
                       q[2*h+1] * sk[base + j][2*h+1]) * inv_sqrt_dh;
            sc[j] = s;
            mx = fmaxf(mx, s);
        }
        float sum = 0.f;
#pragma unroll
        for (int j = 0; j < SEQ; ++j) { sc[j] = expf(sc[j] - mx); sum += sc[j]; }
        const float inv = 1.0f / sum;
        float o0 = 0.f, o1 = 0.f;
#pragma unroll
        for (int j = 0; j < SEQ; ++j) {
            float p = sc[j] * inv;
            o0 += p * sv[base + j][2*h];
            o1 += p * sv[base + j][2*h+1];
        }
        o[2*h] = o0; o[2*h+1] = o1;
    }

    // out_proj: xa[e] = o . opw[e,:] + opb[e]
    float xa[BN];
#pragma unroll
    for (int e = 0; e < BN; ++e) {
        float a = opb[e];
#pragma unroll
        for (int e2 = 0; e2 < BN; ++e2) a += o[e2] * opw[e * BN + e2];
        xa[e] = a;
    }

    const float g = gate[0];

    // expand + residual + LayerNorm over hd=64
    float y[HD];
    float mu = 0.f;
#pragma unroll
    for (int d = 0; d < HD; ++d) {
        float a = eb[d];
#pragma unroll
        for (int e = 0; e < BN; ++e) a += xa[e] * ew[d * BN + e];
        float yy = row[d] + g * a;
        y[d] = yy;
        mu += yy;
    }
    mu *= (1.0f / HD);
    float var = 0.f;
#pragma unroll
    for (int d = 0; d < HD; ++d) { float z = y[d] - mu; var += z * z; }
    var *= (1.0f / HD);
    const float rs = rsqrtf(var + LN_EPS);

#pragma unroll
    for (int d = 0; d < HD; ++d) {
        float outp = (y[d] - mu) * rs * lw[d] + lb[d];
        delta[t * HD + d] = outp - row[d];
    }
}

// ---------------------------------------------------------------------------
// Kernel 3: out = x + delta[slice], broadcast over the 4096 floats of a slice
//
// Two cache levers:
//  * NONTEMPORAL stores for out (kept, +9 us measured): writes don't
//    allocate in the memory-side Infinity Cache, so they don't evict x.
//  * REVERSED slice traversal: pool read x forward, so the LRU stack has
//    the highest slices most-recent. A forward re-read self-thrashes at
//    capacity (x = 256 MiB = L3 size); reading 16383 -> 0 consumes the LRU
//    stack in the order it was built and converts most of the x-read into
//    L3 hits.
// ---------------------------------------------------------------------------
__global__ __launch_bounds__(256) void add_kernel(const float* __restrict__ x,
                                                  const float* __restrict__ delta,
                                                  float* __restrict__ out) {
    const int slice = NSLICE - 1 - blockIdx.x;   // reverse scan vs pool
    const float dv = delta[slice];               // block-uniform scalar
    const size_t off = (size_t)slice * HW;
    const vfloat4* xp = (const vfloat4*)(x + off);
    vfloat4* op = (vfloat4*)(out + off);
    const int t = threadIdx.x;
#pragma unroll
    for (int kk = 0; kk < 4; ++kk) {
        vfloat4 vv = xp[t + kk * 256];
        vv += dv;                           // native vector: element-wise add
        __builtin_nontemporal_store(vv, op + t + kk * 256);
    }
}

// ---------------------------------------------------------------------------
extern "C" void kernel_launch(void* const* d_in, const int* in_sizes, int n_in,
                              void* d_out, int out_size, void* d_ws, size_t ws_size,
                              hipStream_t stream) {
    const float* x   = (const float*)d_in[0];
    const float* cw  = (const float*)d_in[1];
    const float* cb  = (const float*)d_in[2];
    const float* ipw = (const float*)d_in[3];
    const float* ipb = (const float*)d_in[4];
    const float* opw = (const float*)d_in[5];
    const float* opb = (const float*)d_in[6];
    const float* ew  = (const float*)d_in[7];
    const float* eb  = (const float*)d_in[8];
    const float* lw  = (const float*)d_in[9];
    const float* lb  = (const float*)d_in[10];
    const float* gate = (const float*)d_in[11];
    float* out = (float*)d_out;

    float* pooled = (float*)d_ws;           // 16384 floats
    float* delta  = pooled + NSLICE;        // 16384 floats

    pool_kernel<<<NSLICE, 256, 0, stream>>>(x, pooled);
    tiny_kernel<<<1, 256, 0, stream>>>(pooled, cw, cb, ipw, ipb, opw, opb,
                                       ew, eb, lw, lb, gate, delta);
    add_kernel<<<NSLICE, 256, 0, stream>>>(x, delta, out);
}